// Round 16
// baseline (181.981 us; speedup 1.0000x reference)
//
#include <hip/hip_runtime.h>
#include <hip/hip_bf16.h>
#include <cstddef>

// ---------------------------------------------------------------------------
// WTConv2d on MI355X, round 16: barrier-free conv main loop. The FULL 256-cin
// input patch (32KB) is staged to LDS once per block; the 72-step K-loop
// (8 kb x 9 taps) then runs with ZERO barriers (LDS read-only), A weights in
// a ring-6 register pipeline (slot index compile-time via 2x kb unroll),
// next-kb B fragments ping-pong prefetched. MFMA order unchanged from r14
// => bit-identical output.
//
// Xp layout (u16): [B][HP][kblk:8][g:4][WP][e:8], cin = kblk*32+g*8+e
// wT layout (u16): [tap:9][kblk:8][g:4][cout:256][e:8]
// y  layout (u16 bf16): [B][H][W][256] (NHWC)
// ---------------------------------------------------------------------------

typedef __attribute__((ext_vector_type(8))) short short8;   // 8 bf16
typedef __attribute__((ext_vector_type(4))) float f32x4;
typedef __attribute__((ext_vector_type(4))) unsigned short u16x4;

static __device__ __forceinline__ unsigned short f2bf(float f) {
    __hip_bfloat16 h = __float2bfloat16(f);
    return *reinterpret_cast<unsigned short*>(&h);
}
static __device__ __forceinline__ float bf2f(unsigned short u) {
    return __uint_as_float(((unsigned int)u) << 16);
}

static __device__ __forceinline__ void gload_lds16(const short* g, short* l) {
    __builtin_amdgcn_global_load_lds(
        (const __attribute__((address_space(1))) void*)g,
        (__attribute__((address_space(3))) void*)l, 16, 0, 0);
}

// ---- mega prologue: blocks 0..863 weight prep, 864..1205 border zero,
//      1206..3509 DWT level 0 ----
__global__ __launch_bounds__(256) void mega_prep_kernel(
    const float* __restrict__ x,
    const float* __restrict__ wa, const float* __restrict__ wb,
    const float* __restrict__ wc,
    unsigned short* __restrict__ ta, unsigned short* __restrict__ tb,
    unsigned short* __restrict__ tc,
    unsigned short* __restrict__ p0, unsigned short* __restrict__ p1,
    unsigned short* __restrict__ p2)
{
    __shared__ float lds[4 * 64 * 17];
    const int bx = blockIdx.x;
    const int tid = threadIdx.x;
    if (bx < 864) {
        const int sel = bx / 288;
        const float* w = (sel == 0) ? wa : (sel == 1) ? wb : wc;
        unsigned short* wT = (sel == 0) ? ta : (sel == 1) ? tb : tc;
        int idx = (bx - sel * 288) * 256 + tid;   // ((tap*8+kb)*4+g)*256+co
        int co = idx & 255;
        int g = (idx >> 8) & 3;
        int kb = (idx >> 10) & 7;
        int tap = idx >> 13;
        int cin0 = kb * 32 + g * 8;
        unsigned short tmp[8];
#pragma unroll
        for (int e = 0; e < 8; ++e)
            tmp[e] = f2bf(w[((size_t)co * 256 + cin0 + e) * 9 + tap]);
        *(short8*)(wT + (size_t)idx * 8) = *(const short8*)tmp;
        return;
    }
    if (bx < 1206) {
        constexpr int N0 = 49664, N1 = 25088, N2 = 12800;  // 16B border chunks
        int idx = (bx - 864) * 256 + tid;
        unsigned short* base; int HP, WP, rel;
        if (idx < N0)           { base = p0; HP = 98; WP = 98; rel = idx; }
        else if (idx < N0 + N1) { base = p1; HP = 50; WP = 50; rel = idx - N0; }
        else                    { base = p2; HP = 26; WP = 26; rel = idx - N0 - N1; }
        int nb = 64 * WP + (HP - 2) * 64;   // border chunks per batch
        int b = rel / nb, r = rel % nb;
        int row, kg, px;
        if (r < 64 * WP) {
            int rowSel = r / (32 * WP), rr = r % (32 * WP);
            kg = rr / WP; px = rr % WP; row = rowSel ? (HP - 1) : 0;
        } else {
            int r2 = r - 64 * WP;
            row = 1 + (r2 >> 6);
            int r3 = r2 & 63;
            kg = r3 >> 1; px = (r3 & 1) ? (WP - 1) : 0;
        }
        size_t o = (((size_t)(b * HP + row) * 32 + kg) * WP + px) * 8;
        short8 z = {};
        *(short8*)(base + o) = z;
        return;
    }
    // ---- DWT level 0: x NCHW f32 -> Xp0 interior ----
    const int bx2 = bx - 1206;               // 0..2303 = 6 x 96 x 4
    const int j0 = (bx2 % 6) * 16;
    const int i  = (bx2 / 6) % 96;
    const int b  = bx2 / 576;
    const int j = tid & 15;
    const int c4 = tid >> 4;
#pragma unroll
    for (int it = 0; it < 4; ++it) {
        int c = c4 + it * 16;
        const float* p = x + ((size_t)(b * 64 + c) * 192 + 2 * i) * 192 + 2 * (j0 + j);
        float2 top = *(const float2*)p;
        float2 bot = *(const float2*)(p + 192);
        float a = top.x, bb = top.y, cc = bot.x, dd = bot.y;
        const float s2 = 0.25f;
        lds[(0 * 64 + c) * 17 + j] = s2 * (a + bb + cc + dd);
        lds[(1 * 64 + c) * 17 + j] = s2 * (a + bb - cc - dd);
        lds[(2 * 64 + c) * 17 + j] = s2 * (a - bb + cc - dd);
        lds[(3 * 64 + c) * 17 + j] = s2 * (a - bb - cc + dd);
    }
    __syncthreads();
#pragma unroll
    for (int it = 0; it < 2; ++it) {
        int idx = it * 256 + tid;
        int jj = idx & 15;
        int g = (idx >> 4) & 3;
        int kb = idx >> 6;
        int sub = kb >> 1;
        int c0 = (kb & 1) * 32 + g * 8;
        unsigned short tmp[8];
#pragma unroll
        for (int e = 0; e < 8; ++e)
            tmp[e] = f2bf(lds[(sub * 64 + c0 + e) * 17 + jj]);
        size_t o = ((((size_t)(b * 98 + 1 + i) * 8 + kb) * 4 + g) * 98 + 1 + j0 + jj) * 8;
        *(short8*)(p0 + o) = *(const short8*)tmp;
    }
}

// ---- DWT mid: y NHWC bf16 (ch<64 = ll) -> Xp next level ----
template <int H2, int JB>
__global__ __launch_bounds__(256) void dwt_mid_kernel(
    const unsigned short* __restrict__ in, unsigned short* __restrict__ Xp)
{
    constexpr int W2 = H2, Wi = 2 * W2, WPn = W2 + 2, HPn = H2 + 2;
    constexpr int LS = JB + 1;
    __shared__ float lds[4 * 64 * LS];
    const int j0 = blockIdx.x * JB;
    const int i = blockIdx.y;
    const int b = blockIdx.z;
    const int tid = threadIdx.x;
    const int c = tid & 63;
    const int jq = tid >> 6;
#pragma unroll
    for (int it = 0; it < JB / 4; ++it) {
        int jl = jq + it * 4;
        int j = j0 + jl;
        const unsigned short* p = in + ((size_t)(b * 2 * H2 + 2 * i) * Wi + 2 * j) * 256 + c;
        float a  = bf2f(p[0]);
        float bb = bf2f(p[256]);
        float cc = bf2f(p[(size_t)Wi * 256]);
        float dd = bf2f(p[(size_t)Wi * 256 + 256]);
        const float s2 = 0.25f;
        lds[(0 * 64 + c) * LS + jl] = s2 * (a + bb + cc + dd);
        lds[(1 * 64 + c) * LS + jl] = s2 * (a + bb - cc - dd);
        lds[(2 * 64 + c) * LS + jl] = s2 * (a - bb + cc - dd);
        lds[(3 * 64 + c) * LS + jl] = s2 * (a - bb - cc + dd);
    }
    __syncthreads();
    constexpr int CH = 8 * 4 * JB;
#pragma unroll
    for (int it = 0; it < (CH + 255) / 256; ++it) {
        int idx = it * 256 + tid;
        if (idx < CH) {
            int jj = idx % JB;
            int g = (idx / JB) & 3;
            int kb = idx / (JB * 4);
            int sub = kb >> 1;
            int c0 = (kb & 1) * 32 + g * 8;
            unsigned short tmp[8];
#pragma unroll
            for (int e = 0; e < 8; ++e)
                tmp[e] = f2bf(lds[(sub * 64 + c0 + e) * LS + jj]);
            size_t o = ((((size_t)(b * HPn + 1 + i) * 8 + kb) * 4 + g) * WPn + 1 + j0 + jj) * 8;
            *(short8*)(Xp + o) = *(const short8*)tmp;
        }
    }
}

// ---- conv: full-patch LDS, barrier-free 72-step K-loop ----
// Block: 64 couts x (4x8) pixels, 2 waves (row-split). Full 256-cin patch
// (32KB) staged once; A in ring-6 (slot = (3p+s)%6, p = kb parity), Br
// ping-pong prefetched one kb ahead.
template <int HP, int WP, int XCHUNK>
__global__ __launch_bounds__(128) void conv_full_kernel(
    const short* __restrict__ Xp, const short* __restrict__ Wt,
    unsigned short* __restrict__ Y)
{
    constexpr int PR = 4, PC = 8, MFR = 4;
    constexpr int H = HP - 2, W = WP - 2;
    constexpr int rowT = H / PR, colT = W / PC;
    constexpr int PH = PR + 2, PW = PC + 2;
    constexpr int RAW = PH * PW;              // 60
    constexpr int SLOT = (RAW + 63) & ~63;    // 64
    constexpr int TIW = 16;                   // staging insts per wave (32 total)
    constexpr size_t S_r = (size_t)256 * WP;
    constexpr size_t S_kb = (size_t)32 * WP;
    constexpr size_t S_g = (size_t)8 * WP;

    __shared__ __align__(16) short lsB[8 * 4 * SLOT * 8];   // 32 KB

    int bid = blockIdx.x;
    if (XCHUNK > 0) bid = (bid & 7) * XCHUNK + (bid >> 3);
    const int tx = bid % colT; bid /= colT;
    const int ty = bid % rowT; bid /= rowT;
    const int b = bid;
    const int gy0 = ty * PR;
    const int gx0 = tx * PC;
    const int cb = blockIdx.y * 64;

    const int lane = threadIdx.x & 63;
    const int wn = threadIdx.x >> 6;          // 0..1
    const int n15 = lane & 15, gq = lane >> 4;

    const size_t bBase = (size_t)(b * HP + gy0) * S_r + (size_t)gx0 * 8;

    // ---- stage FULL patch once (addresses computed inline, transient) ----
#pragma unroll
    for (int ti = 0; ti < TIW; ++ti) {
        int d = (wn * TIW + ti) * 64 + lane;   // 0..2047
        int kb = d >> 8;
        int r = d & 255;
        int g = r >> 6;
        int slot = r & 63;
        int prow = slot / PW, pcol = slot % PW;
        size_t src = (slot < RAW)
            ? bBase + (size_t)prow * S_r + (size_t)kb * S_kb
              + (size_t)g * S_g + (size_t)pcol * 8
            : bBase;
        gload_lds16(Xp + src, &lsB[(size_t)d * 8]);
    }

    const short* aBase = Wt + (size_t)gq * 2048 + (size_t)(cb + n15) * 8;
    const int rB = wn * 2 + n15 / PC;
    const int cB = n15 % PC;
    const int bSlot = gq * SLOT + rB * PW + cB;   // within-kb lane base

    f32x4 acc[MFR] = {};
    short8 a[6][MFR];                      // ring-6
    short8 BrA[3][3], BrB[3][3];

    auto ldA = [&](int tap, int kbv, int m) -> short8 {
        return *(const short8*)(aBase + (size_t)tap * 65536
                                + (size_t)kbv * 8192 + m * 128);
    };
    auto ldBr = [&](int kbv, short8 (*Br)[3]) {
#pragma unroll
        for (int ky = 0; ky < 3; ++ky)
#pragma unroll
            for (int kx = 0; kx < 3; ++kx)
                Br[ky][kx] = *(const short8*)&lsB[
                    (size_t)(kbv * 256 + bSlot + ky * PW + kx) * 8];
    };

    // preload A steps 0..5 (taps 0..5 of kb0) while staging lands
#pragma unroll
    for (int s = 0; s < 6; ++s)
#pragma unroll
        for (int m = 0; m < MFR; ++m)
            a[s][m] = ldA(s, 0, m);

    asm volatile("s_waitcnt vmcnt(0)" ::: "memory");
    __builtin_amdgcn_sched_barrier(0);
    __builtin_amdgcn_s_barrier();          // the ONLY barrier

    ldBr(0, BrA);

    // kbBody: compute kb (parity P) using cur Br; prefetch nxt Br for kb+1.
    auto kbBody = [&](int kb, int P, short8 (*cur)[3], short8 (*nxt)[3]) {
        const int kbn = (kb < 7) ? kb + 1 : 7;
        ldBr(kbn, nxt);                    // hidden under this kb's MFMAs
#pragma unroll
        for (int s = 0; s < 9; ++s) {
            const int ky = s / 3, kx = s - 3 * ky;
            const int rs = (3 * P + s) % 6;            // compile-time
            __builtin_amdgcn_s_setprio(1);
#pragma unroll
            for (int m = 0; m < MFR; ++m)
                acc[m] = __builtin_amdgcn_mfma_f32_16x16x32_bf16(
                    a[rs][m], cur[ky][kx], acc[m], 0, 0, 0);
            __builtin_amdgcn_s_setprio(0);
            // refill slot rs with step kb*9+s+6
            const int ftap = (s + 6 < 9) ? s + 6 : s - 3;
            const int fkb  = (s + 6 < 9) ? kb : kbn;
#pragma unroll
            for (int m = 0; m < MFR; ++m)
                a[rs][m] = ldA(ftap, fkb, m);
        }
    };

#pragma unroll 1
    for (int u = 0; u < 4; ++u) {
        kbBody(2 * u,     0, BrA, BrB);
        kbBody(2 * u + 1, 1, BrB, BrA);
    }

    // D: col(lane&15)=pixel, row=(lane>>4)*4+reg=cout-within-16; store bf16
#pragma unroll
    for (int m = 0; m < MFR; ++m) {
        int cout = cb + m * 16 + gq * 4;
        int row = gy0 + rB;
        int col = gx0 + cB;
        unsigned short* op = Y + ((size_t)(b * H + row) * W + col) * 256 + cout;
        u16x4 sv;
#pragma unroll
        for (int q = 0; q < 4; ++q) sv[q] = f2bf(acc[m][q]);
        *(u16x4*)op = sv;
    }
}

// ---- fused 3-level IDWT + bias -> out NCHW f32 ----
__global__ __launch_bounds__(256) void idwt_fused_kernel(
    const unsigned short* __restrict__ y2, const unsigned short* __restrict__ y1,
    const unsigned short* __restrict__ y0h,
    const float* __restrict__ bias, float* __restrict__ out)
{
    __shared__ float lds[16 * 324];
    const int tt = blockIdx.x;               // 12x12 tiles of 8x8 ll0-px
    const int tyi = tt / 12, txi = tt % 12;
    const int y0 = tyi * 8, x0 = txi * 8;
    const int cg = blockIdx.y;               // 0..3
    const int b = blockIdx.z;
    const int tid = threadIdx.x;

#pragma unroll
    for (int rep = 0; rep < 4; ++rep) {
        int idx = rep * 256 + tid;
        int c16 = idx & 15;
        int px = idx >> 4;                   // 0..63
        int pi = px >> 3, pj = px & 7;
        int c = cg * 16 + c16;
        int pi96 = y0 + pi, pj96 = x0 + pj;
        int pi48 = pi96 >> 1, pj48 = pj96 >> 1;
        int pi24 = pi48 >> 1, pj24 = pj48 >> 1;
        const unsigned short* h2 = y2 + ((size_t)(b * 24 + pi24) * 24 + pj24) * 256;
        float l2   = bf2f(h2[c]);
        float l2lh = bf2f(h2[64 + c]);
        float l2hl = bf2f(h2[128 + c]);
        float l2hh = bf2f(h2[192 + c]);
        float s1 = 1.f - 2.f * (pi48 & 1), t1 = 1.f - 2.f * (pj48 & 1);
        float ll1v = l2 + s1 * l2lh + t1 * l2hl + (s1 * t1) * l2hh;
        const unsigned short* h1 = y1 + ((size_t)(b * 48 + pi48) * 48 + pj48) * 256;
        float l1lh = bf2f(h1[64 + c]);
        float l1hl = bf2f(h1[128 + c]);
        float l1hh = bf2f(h1[192 + c]);
        float s0 = 1.f - 2.f * (pi96 & 1), t0 = 1.f - 2.f * (pj96 & 1);
        float vll = ll1v + s0 * l1lh + t0 * l1hl + (s0 * t0) * l1hh;
        const unsigned short* hp = y0h + ((size_t)(b * 96 + pi96) * 96 + pj96) * 256;
        float vlh = bf2f(hp[64 + c]);
        float vhl = bf2f(hp[128 + c]);
        float vhh = bf2f(hp[192 + c]);
        float bv = bias[c];
        float a  = vll + vlh + vhl + vhh + bv;
        float b2 = vll + vlh - vhl - vhh + bv;
        float c2 = vll - vlh + vhl - vhh + bv;
        float d2 = vll - vlh - vhl + vhh + bv;
        float* l = lds + c16 * 324 + (2 * pi) * 20 + 2 * pj;
        l[0] = a; l[1] = b2;
        l[20] = c2; l[21] = d2;
    }
    __syncthreads();

    const int c16 = tid >> 4;
    const int yy = tid & 15;
    const float* l = lds + c16 * 324 + yy * 20;
    float* op = out + ((size_t)(b * 64 + cg * 16 + c16) * 192 + tyi * 16 + yy) * 192 + txi * 16;
#pragma unroll
    for (int q = 0; q < 4; ++q)
        *(f32x4*)(op + 4 * q) = *(const f32x4*)(l + 4 * q);
}

extern "C" void kernel_launch(void* const* d_in, const int* in_sizes, int n_in,
                              void* d_out, int out_size, void* d_ws, size_t ws_size,
                              hipStream_t stream)
{
    const float* x    = (const float*)d_in[0];
    const float* w0   = (const float*)d_in[1];
    const float* w1   = (const float*)d_in[2];
    const float* w2   = (const float*)d_in[3];
    const float* bias = (const float*)d_in[4];
    float* out = (float*)d_out;

    char* ws = (char*)d_ws;
    unsigned short* wT0 = (unsigned short*)(ws + 0);          // 1,179,648 B
    unsigned short* wT1 = (unsigned short*)(ws + 1179648);
    unsigned short* wT2 = (unsigned short*)(ws + 2359296);
    unsigned short* Xp0 = (unsigned short*)(ws + 3538944);    // 19,668,992 B
    unsigned short* Xp1 = (unsigned short*)(ws + 23207936);   //  5,120,000 B
    unsigned short* Xp2 = (unsigned short*)(ws + 28327936);   //  1,384,448 B
    unsigned short* y0 = (unsigned short*)(ws + 29712384);    // 18,874,368 B
    unsigned short* y1 = (unsigned short*)(ws + 48586752);    //  4,718,592 B
    unsigned short* y2 = (unsigned short*)(ws + 53305344);    //  1,179,648 B

    mega_prep_kernel<<<3510, 256, 0, stream>>>(x, w0, w1, w2, wT0, wT1, wT2,
                                               Xp0, Xp1, Xp2);

    // 96x96: pixel tiles (96/4)x(96/8)x4 = 1152 (=8*144), 4 cout slices
    conv_full_kernel<98, 98, 144><<<dim3(1152, 4), 128, 0, stream>>>(
        (const short*)Xp0, (const short*)wT0, y0);

    dwt_mid_kernel<48, 16><<<dim3(3, 48, 4), 256, 0, stream>>>(y0, Xp1);
    // 48x48: tiles 12x6x4 = 288 (=8*36), 4 cout slices
    conv_full_kernel<50, 50, 36><<<dim3(288, 4), 128, 0, stream>>>(
        (const short*)Xp1, (const short*)wT1, y1);

    dwt_mid_kernel<24, 12><<<dim3(2, 24, 4), 256, 0, stream>>>(y1, Xp2);
    // 24x24: tiles 6x3x4 = 72 (=8*9), 4 cout slices
    conv_full_kernel<26, 26, 9><<<dim3(72, 4), 128, 0, stream>>>(
        (const short*)Xp2, (const short*)wT2, y2);

    idwt_fused_kernel<<<dim3(144, 4, 4), 256, 0, stream>>>(y2, y1, y0, bias, out);
}

// Round 17
// 131.872 us; speedup vs baseline: 1.3800x; 1.3800x over previous
//
#include <hip/hip_runtime.h>
#include <hip/hip_bf16.h>
#include <cstddef>

// ---------------------------------------------------------------------------
// WTConv2d on MI355X, round 17: round-14 (best, 134.6us) + pinned counted
// vmcnt(36) per-kb drain (r15-proven safe) instead of vmcnt(0): the 36
// A-refill loads stay in flight across the kb barrier; only the LDS stage
// (issue-pinned oldest) is forced to land. Trailing vmcnt(0) at block exit.
//
// Xp layout (u16): [B][HP][kblk:8][g:4][WP][e:8], cin = kblk*32+g*8+e
// wT layout (u16): [tap:9][kblk:8][g:4][cout:256][e:8]
// y  layout (u16 bf16): [B][H][W][256] (NHWC)
// ---------------------------------------------------------------------------

typedef __attribute__((ext_vector_type(8))) short short8;   // 8 bf16
typedef __attribute__((ext_vector_type(4))) float f32x4;
typedef __attribute__((ext_vector_type(4))) unsigned short u16x4;

static __device__ __forceinline__ unsigned short f2bf(float f) {
    __hip_bfloat16 h = __float2bfloat16(f);
    return *reinterpret_cast<unsigned short*>(&h);
}
static __device__ __forceinline__ float bf2f(unsigned short u) {
    return __uint_as_float(((unsigned int)u) << 16);
}

static __device__ __forceinline__ void gload_lds16(const short* g, short* l) {
    __builtin_amdgcn_global_load_lds(
        (const __attribute__((address_space(1))) void*)g,
        (__attribute__((address_space(3))) void*)l, 16, 0, 0);
}

// ---- mega prologue: blocks 0..863 weight prep, 864..1205 border zero,
//      1206..3509 DWT level 0 ----
__global__ __launch_bounds__(256) void mega_prep_kernel(
    const float* __restrict__ x,
    const float* __restrict__ wa, const float* __restrict__ wb,
    const float* __restrict__ wc,
    unsigned short* __restrict__ ta, unsigned short* __restrict__ tb,
    unsigned short* __restrict__ tc,
    unsigned short* __restrict__ p0, unsigned short* __restrict__ p1,
    unsigned short* __restrict__ p2)
{
    __shared__ float lds[4 * 64 * 17];
    const int bx = blockIdx.x;
    const int tid = threadIdx.x;
    if (bx < 864) {
        const int sel = bx / 288;
        const float* w = (sel == 0) ? wa : (sel == 1) ? wb : wc;
        unsigned short* wT = (sel == 0) ? ta : (sel == 1) ? tb : tc;
        int idx = (bx - sel * 288) * 256 + tid;   // ((tap*8+kb)*4+g)*256+co
        int co = idx & 255;
        int g = (idx >> 8) & 3;
        int kb = (idx >> 10) & 7;
        int tap = idx >> 13;
        int cin0 = kb * 32 + g * 8;
        unsigned short tmp[8];
#pragma unroll
        for (int e = 0; e < 8; ++e)
            tmp[e] = f2bf(w[((size_t)co * 256 + cin0 + e) * 9 + tap]);
        *(short8*)(wT + (size_t)idx * 8) = *(const short8*)tmp;
        return;
    }
    if (bx < 1206) {
        constexpr int N0 = 49664, N1 = 25088, N2 = 12800;  // 16B border chunks
        int idx = (bx - 864) * 256 + tid;
        unsigned short* base; int HP, WP, rel;
        if (idx < N0)           { base = p0; HP = 98; WP = 98; rel = idx; }
        else if (idx < N0 + N1) { base = p1; HP = 50; WP = 50; rel = idx - N0; }
        else                    { base = p2; HP = 26; WP = 26; rel = idx - N0 - N1; }
        int nb = 64 * WP + (HP - 2) * 64;   // border chunks per batch
        int b = rel / nb, r = rel % nb;
        int row, kg, px;
        if (r < 64 * WP) {
            int rowSel = r / (32 * WP), rr = r % (32 * WP);
            kg = rr / WP; px = rr % WP; row = rowSel ? (HP - 1) : 0;
        } else {
            int r2 = r - 64 * WP;
            row = 1 + (r2 >> 6);
            int r3 = r2 & 63;
            kg = r3 >> 1; px = (r3 & 1) ? (WP - 1) : 0;
        }
        size_t o = (((size_t)(b * HP + row) * 32 + kg) * WP + px) * 8;
        short8 z = {};
        *(short8*)(base + o) = z;
        return;
    }
    // ---- DWT level 0: x NCHW f32 -> Xp0 interior ----
    const int bx2 = bx - 1206;               // 0..2303 = 6 x 96 x 4
    const int j0 = (bx2 % 6) * 16;
    const int i  = (bx2 / 6) % 96;
    const int b  = bx2 / 576;
    const int j = tid & 15;
    const int c4 = tid >> 4;
#pragma unroll
    for (int it = 0; it < 4; ++it) {
        int c = c4 + it * 16;
        const float* p = x + ((size_t)(b * 64 + c) * 192 + 2 * i) * 192 + 2 * (j0 + j);
        float2 top = *(const float2*)p;
        float2 bot = *(const float2*)(p + 192);
        float a = top.x, bb = top.y, cc = bot.x, dd = bot.y;
        const float s2 = 0.25f;
        lds[(0 * 64 + c) * 17 + j] = s2 * (a + bb + cc + dd);
        lds[(1 * 64 + c) * 17 + j] = s2 * (a + bb - cc - dd);
        lds[(2 * 64 + c) * 17 + j] = s2 * (a - bb + cc - dd);
        lds[(3 * 64 + c) * 17 + j] = s2 * (a - bb - cc + dd);
    }
    __syncthreads();
#pragma unroll
    for (int it = 0; it < 2; ++it) {
        int idx = it * 256 + tid;
        int jj = idx & 15;
        int g = (idx >> 4) & 3;
        int kb = idx >> 6;
        int sub = kb >> 1;
        int c0 = (kb & 1) * 32 + g * 8;
        unsigned short tmp[8];
#pragma unroll
        for (int e = 0; e < 8; ++e)
            tmp[e] = f2bf(lds[(sub * 64 + c0 + e) * 17 + jj]);
        size_t o = ((((size_t)(b * 98 + 1 + i) * 8 + kb) * 4 + g) * 98 + 1 + j0 + jj) * 8;
        *(short8*)(p0 + o) = *(const short8*)tmp;
    }
}

// ---- DWT mid: y NHWC bf16 (ch<64 = ll) -> Xp next level ----
template <int H2, int JB>
__global__ __launch_bounds__(256) void dwt_mid_kernel(
    const unsigned short* __restrict__ in, unsigned short* __restrict__ Xp)
{
    constexpr int W2 = H2, Wi = 2 * W2, WPn = W2 + 2, HPn = H2 + 2;
    constexpr int LS = JB + 1;
    __shared__ float lds[4 * 64 * LS];
    const int j0 = blockIdx.x * JB;
    const int i = blockIdx.y;
    const int b = blockIdx.z;
    const int tid = threadIdx.x;
    const int c = tid & 63;
    const int jq = tid >> 6;
#pragma unroll
    for (int it = 0; it < JB / 4; ++it) {
        int jl = jq + it * 4;
        int j = j0 + jl;
        const unsigned short* p = in + ((size_t)(b * 2 * H2 + 2 * i) * Wi + 2 * j) * 256 + c;
        float a  = bf2f(p[0]);
        float bb = bf2f(p[256]);
        float cc = bf2f(p[(size_t)Wi * 256]);
        float dd = bf2f(p[(size_t)Wi * 256 + 256]);
        const float s2 = 0.25f;
        lds[(0 * 64 + c) * LS + jl] = s2 * (a + bb + cc + dd);
        lds[(1 * 64 + c) * LS + jl] = s2 * (a + bb - cc - dd);
        lds[(2 * 64 + c) * LS + jl] = s2 * (a - bb + cc - dd);
        lds[(3 * 64 + c) * LS + jl] = s2 * (a - bb - cc + dd);
    }
    __syncthreads();
    constexpr int CH = 8 * 4 * JB;
#pragma unroll
    for (int it = 0; it < (CH + 255) / 256; ++it) {
        int idx = it * 256 + tid;
        if (idx < CH) {
            int jj = idx % JB;
            int g = (idx / JB) & 3;
            int kb = idx / (JB * 4);
            int sub = kb >> 1;
            int c0 = (kb & 1) * 32 + g * 8;
            unsigned short tmp[8];
#pragma unroll
            for (int e = 0; e < 8; ++e)
                tmp[e] = f2bf(lds[(sub * 64 + c0 + e) * LS + jj]);
            size_t o = ((((size_t)(b * HPn + 1 + i) * 8 + kb) * 4 + g) * WPn + 1 + j0 + jj) * 8;
            *(short8*)(Xp + o) = *(const short8*)tmp;
        }
    }
}

// ---- conv: register-pipeline implicit GEMM, 2-wave 64-cout blocks ----
// Per kb: stage(kb+1) pinned early (oldest VMEM); B frags hoisted; A 3-tap
// ring refilled after use; pinned counted vmcnt(36) + barrier per kb.
template <int HP, int WP, int PR, int PC, int XCHUNK>
__global__ __launch_bounds__(128) void conv_reg_kernel(
    const short* __restrict__ Xp, const short* __restrict__ Wt,
    unsigned short* __restrict__ Y)
{
    constexpr int WN = 2;
    constexpr int NPX = PR * PC;
    constexpr int MFR = 4;                 // 64 couts per wave
    constexpr int NFR = NPX / (16 * WN);   // 16-px frags per wave
    constexpr int RPF = 16 / PC;           // rows per 16-px frag
    constexpr int BROWS = (NFR - 1) * RPF + 3;
    constexpr int H = HP - 2, W = WP - 2;
    constexpr int rowT = H / PR, colT = W / PC;
    constexpr int PH = PR + 2, PW = PC + 2;
    constexpr int RAW = PH * PW;
    constexpr int SLOTG = (RAW + 63) & ~63;   // 16B slots per g (1KB insts)
    constexpr int TI = 4 * SLOTG / 64;        // stage insts per kb buffer
    constexpr int TIW = TI / WN;              // per wave
    constexpr size_t S_r = (size_t)256 * WP;
    constexpr size_t S_kb = (size_t)32 * WP;
    constexpr size_t S_g = (size_t)8 * WP;

    __shared__ __align__(16) short bufA[4 * SLOTG * 8];
    __shared__ __align__(16) short bufB[4 * SLOTG * 8];

    int bid = blockIdx.x;
    if (XCHUNK > 0) bid = (bid & 7) * XCHUNK + (bid >> 3);
    const int tx = bid % colT; bid /= colT;
    const int ty = bid % rowT; bid /= rowT;
    const int b = bid;
    const int gy0 = ty * PR;
    const int gx0 = tx * PC;
    const int cb = blockIdx.y * 64;

    const int lane = threadIdx.x & 63;
    const int wn = threadIdx.x >> 6;          // 0..1
    const int n15 = lane & 15, gq = lane >> 4;

    const size_t bBase = (size_t)(b * HP + gy0) * S_r + (size_t)gx0 * 8;

    size_t sSrc[TIW]; int sDst[TIW];
#pragma unroll
    for (int ti = 0; ti < TIW; ++ti) {
        int t = wn * TIW + ti;
        int d = t * 64 + lane;
        int g = d / SLOTG;
        int p = d - g * SLOTG;
        int prow = p / PW, pcol = p - prow * PW;
        sDst[ti] = d * 8;
        sSrc[ti] = (p < RAW)
            ? bBase + (size_t)prow * S_r + (size_t)g * S_g + (size_t)pcol * 8
            : bBase;
    }

    const short* aBase = Wt + (size_t)gq * 2048 + (size_t)(cb + n15) * 8;
    const int rB = wn * (PR / WN) + n15 / PC;
    const int cB = n15 % PC;
    const int bSlot = gq * SLOTG + rB * PW + cB;

    f32x4 acc[MFR][NFR] = {};
    short8 a[3][MFR];

    auto stage = [&](int kbv, short* dBuf) {
#pragma unroll
        for (int ti = 0; ti < TIW; ++ti)
            gload_lds16(Xp + sSrc[ti] + (size_t)kbv * S_kb, dBuf + sDst[ti]);
    };
    auto ldA = [&](int tap, int kbv, int m) -> short8 {
        return *(const short8*)(aBase + (size_t)tap * 65536
                                + (size_t)kbv * 8192 + m * 128);
    };

    stage(0, bufA);
#pragma unroll
    for (int s = 0; s < 3; ++s)
#pragma unroll
        for (int m = 0; m < MFR; ++m)
            a[s][m] = ldA(s, 0, m);
    asm volatile("s_waitcnt vmcnt(0)" ::: "memory");
    __builtin_amdgcn_sched_barrier(0);
    __builtin_amdgcn_s_barrier();

    auto kbBody = [&](int kb, const short* cur, short* nxt) {
        const int kbn = (kb < 7) ? kb + 1 : 7;
        stage(kbn, nxt);                     // issue early: oldest VMEM ops
        __builtin_amdgcn_sched_barrier(0);   // pin stage issue before compute
        short8 Br[BROWS][3];
#pragma unroll
        for (int r = 0; r < BROWS; ++r)
#pragma unroll
            for (int kx = 0; kx < 3; ++kx)
                Br[r][kx] = *(const short8*)(cur + (bSlot + r * PW + kx) * 8);
#pragma unroll
        for (int s = 0; s < 9; ++s) {
            const int ky = s / 3, kx = s - 3 * (s / 3);
            const int rs = s % 3;
            __builtin_amdgcn_s_setprio(1);
#pragma unroll
            for (int m = 0; m < MFR; ++m)
#pragma unroll
                for (int n = 0; n < NFR; ++n)
                    acc[m][n] = __builtin_amdgcn_mfma_f32_16x16x32_bf16(
                        a[rs][m], Br[n * RPF + ky][kx], acc[m][n], 0, 0, 0);
            __builtin_amdgcn_s_setprio(0);
            const int ft = s + 3;
            const int ftap = (ft < 9) ? ft : ft - 9;
            const int fkb = (ft < 9) ? kb : kbn;
#pragma unroll
            for (int m = 0; m < MFR; ++m)
                a[rs][m] = ldA(ftap, fkb, m);
        }
        // counted drain: 36 A-refills issued after the pinned stage; vmcnt
        // retires in issue order, so outstanding<=36 => stage landed. The
        // A register values are tracked by compiler-inserted waits.
        __builtin_amdgcn_sched_barrier(0);
        asm volatile("s_waitcnt vmcnt(36)" ::: "memory");
        __builtin_amdgcn_sched_barrier(0);
        __builtin_amdgcn_s_barrier();
    };

#pragma unroll 1
    for (int u = 0; u < 4; ++u) {
        kbBody(2 * u, bufA, bufB);
        kbBody(2 * u + 1, bufB, bufA);
    }
    // drain all DMAs before block exit (LDS may be reassigned)
    asm volatile("s_waitcnt vmcnt(0)" ::: "memory");

    // D: col(lane&15)=pixel, row=(lane>>4)*4+reg=cout-within-16; store bf16
#pragma unroll
    for (int m = 0; m < MFR; ++m)
#pragma unroll
        for (int n = 0; n < NFR; ++n) {
            int cout = cb + m * 16 + gq * 4;
            int row = wn * (PR / WN) + n * RPF + n15 / PC;
            int col = n15 % PC;
            unsigned short* op = Y + ((size_t)(b * H + gy0 + row) * W + gx0 + col) * 256 + cout;
            u16x4 sv;
#pragma unroll
            for (int q = 0; q < 4; ++q) sv[q] = f2bf(acc[m][n][q]);
            *(u16x4*)op = sv;
        }
}

// ---- fused 3-level IDWT + bias -> out NCHW f32 ----
__global__ __launch_bounds__(256) void idwt_fused_kernel(
    const unsigned short* __restrict__ y2, const unsigned short* __restrict__ y1,
    const unsigned short* __restrict__ y0h,
    const float* __restrict__ bias, float* __restrict__ out)
{
    __shared__ float lds[16 * 324];
    const int tt = blockIdx.x;               // 12x12 tiles of 8x8 ll0-px
    const int tyi = tt / 12, txi = tt % 12;
    const int y0 = tyi * 8, x0 = txi * 8;
    const int cg = blockIdx.y;               // 0..3
    const int b = blockIdx.z;
    const int tid = threadIdx.x;

#pragma unroll
    for (int rep = 0; rep < 4; ++rep) {
        int idx = rep * 256 + tid;
        int c16 = idx & 15;
        int px = idx >> 4;                   // 0..63
        int pi = px >> 3, pj = px & 7;
        int c = cg * 16 + c16;
        int pi96 = y0 + pi, pj96 = x0 + pj;
        int pi48 = pi96 >> 1, pj48 = pj96 >> 1;
        int pi24 = pi48 >> 1, pj24 = pj48 >> 1;
        const unsigned short* h2 = y2 + ((size_t)(b * 24 + pi24) * 24 + pj24) * 256;
        float l2   = bf2f(h2[c]);
        float l2lh = bf2f(h2[64 + c]);
        float l2hl = bf2f(h2[128 + c]);
        float l2hh = bf2f(h2[192 + c]);
        float s1 = 1.f - 2.f * (pi48 & 1), t1 = 1.f - 2.f * (pj48 & 1);
        float ll1v = l2 + s1 * l2lh + t1 * l2hl + (s1 * t1) * l2hh;
        const unsigned short* h1 = y1 + ((size_t)(b * 48 + pi48) * 48 + pj48) * 256;
        float l1lh = bf2f(h1[64 + c]);
        float l1hl = bf2f(h1[128 + c]);
        float l1hh = bf2f(h1[192 + c]);
        float s0 = 1.f - 2.f * (pi96 & 1), t0 = 1.f - 2.f * (pj96 & 1);
        float vll = ll1v + s0 * l1lh + t0 * l1hl + (s0 * t0) * l1hh;
        const unsigned short* hp = y0h + ((size_t)(b * 96 + pi96) * 96 + pj96) * 256;
        float vlh = bf2f(hp[64 + c]);
        float vhl = bf2f(hp[128 + c]);
        float vhh = bf2f(hp[192 + c]);
        float bv = bias[c];
        float a  = vll + vlh + vhl + vhh + bv;
        float b2 = vll + vlh - vhl - vhh + bv;
        float c2 = vll - vlh + vhl - vhh + bv;
        float d2 = vll - vlh - vhl + vhh + bv;
        float* l = lds + c16 * 324 + (2 * pi) * 20 + 2 * pj;
        l[0] = a; l[1] = b2;
        l[20] = c2; l[21] = d2;
    }
    __syncthreads();

    const int c16 = tid >> 4;
    const int yy = tid & 15;
    const float* l = lds + c16 * 324 + yy * 20;
    float* op = out + ((size_t)(b * 64 + cg * 16 + c16) * 192 + tyi * 16 + yy) * 192 + txi * 16;
#pragma unroll
    for (int q = 0; q < 4; ++q)
        *(f32x4*)(op + 4 * q) = *(const f32x4*)(l + 4 * q);
}

extern "C" void kernel_launch(void* const* d_in, const int* in_sizes, int n_in,
                              void* d_out, int out_size, void* d_ws, size_t ws_size,
                              hipStream_t stream)
{
    const float* x    = (const float*)d_in[0];
    const float* w0   = (const float*)d_in[1];
    const float* w1   = (const float*)d_in[2];
    const float* w2   = (const float*)d_in[3];
    const float* bias = (const float*)d_in[4];
    float* out = (float*)d_out;

    char* ws = (char*)d_ws;
    unsigned short* wT0 = (unsigned short*)(ws + 0);          // 1,179,648 B
    unsigned short* wT1 = (unsigned short*)(ws + 1179648);
    unsigned short* wT2 = (unsigned short*)(ws + 2359296);
    unsigned short* Xp0 = (unsigned short*)(ws + 3538944);    // 19,668,992 B
    unsigned short* Xp1 = (unsigned short*)(ws + 23207936);   //  5,120,000 B
    unsigned short* Xp2 = (unsigned short*)(ws + 28327936);   //  1,384,448 B
    unsigned short* y0 = (unsigned short*)(ws + 29712384);    // 18,874,368 B
    unsigned short* y1 = (unsigned short*)(ws + 48586752);    //  4,718,592 B
    unsigned short* y2 = (unsigned short*)(ws + 53305344);    //  1,179,648 B

    mega_prep_kernel<<<3510, 256, 0, stream>>>(x, w0, w1, w2, wT0, wT1, wT2,
                                               Xp0, Xp1, Xp2);

    // 96x96: tiles (96/4)x(96/16)x4 = 576 (=8*72), 4 cout slices
    conv_reg_kernel<98, 98, 4, 16, 72><<<dim3(576, 4), 128, 0, stream>>>(
        (const short*)Xp0, (const short*)wT0, y0);

    dwt_mid_kernel<48, 16><<<dim3(3, 48, 4), 256, 0, stream>>>(y0, Xp1);
    // 48x48: tiles 12x3x4 = 144 (=8*18), 4 cout slices
    conv_reg_kernel<50, 50, 4, 16, 18><<<dim3(144, 4), 128, 0, stream>>>(
        (const short*)Xp1, (const short*)wT1, y1);

    dwt_mid_kernel<24, 12><<<dim3(2, 24, 4), 256, 0, stream>>>(y1, Xp2);
    // 24x24: tiles (24/4)x(24/8)x4 = 72 (=8*9), 4 cout slices
    conv_reg_kernel<26, 26, 4, 8, 9><<<dim3(72, 4), 128, 0, stream>>>(
        (const short*)Xp2, (const short*)wT2, y2);

    idwt_fused_kernel<<<dim3(144, 4, 4), 256, 0, stream>>>(y2, y1, y0, bias, out);
}